// Round 4
// baseline (306.851 us; speedup 1.0000x reference)
//
#include <hip/hip_runtime.h>

// Problem constants (match reference)
constexpr int BB = 2;
constexpr int DD = 128;   // MAXDISP
constexpr int HH = 384;
constexpr int WW = 768;
constexpr int W4 = WW / 4;   // 192 int4/float4 per row
constexpr int DG = 32;       // disparities per block
constexpr int QG = DG / 4;   // int4-window steps per block (8)

__global__ __launch_bounds__(192) void Hamming_34205119545967_kernel(
    const int* __restrict__ img1, const int* __restrict__ img2,
    const float* __restrict__ scale, float* __restrict__ out) {
    const int h  = blockIdx.x;   // 0..383
    const int dg = blockIdx.y;   // 0..3  (d group)
    const int b  = blockIdx.z;   // 0..1
    const int x4 = threadIdx.x;  // 0..191, one float4 column slice

    const int4* __restrict__ L4 =
        reinterpret_cast<const int4*>(img1 + ((size_t)b * HH + h) * WW);
    const int4* __restrict__ R4 =
        reinterpret_cast<const int4*>(img2 + ((size_t)b * HH + h) * WW);

    const int4  r = R4[x4];      // loop-invariant right word
    const float s = scale[0];

    int q = dg * QG;             // left-window word offset, d = 4q + rm
    int4 A = L4[min(x4 + q, W4 - 1)];

    const size_t drow = (size_t)HH * W4;  // float4 stride between d planes
    float4* __restrict__ obase = reinterpret_cast<float4*>(out) +
        (((size_t)b * DD + (dg * DG)) * HH + h) * W4 + x4;

#define EMIT(w0, w1, w2, w3, rm)                                       \
    {                                                                  \
        const int o_ = off0 + (rm);                                    \
        float4 o;                                                      \
        o.x = (o_ + 0 < WW) ? (float)__popc((w0) ^ r.x) * s : 0.0f;    \
        o.y = (o_ + 1 < WW) ? (float)__popc((w1) ^ r.y) * s : 0.0f;    \
        o.z = (o_ + 2 < WW) ? (float)__popc((w2) ^ r.z) * s : 0.0f;    \
        o.w = (o_ + 3 < WW) ? (float)__popc((w3) ^ r.w) * s : 0.0f;    \
        obase[(size_t)(4 * qq + (rm)) * drow] = o;                     \
    }

#pragma unroll
    for (int qq = 0; qq < QG; ++qq, ++q) {
        const int4 Bv = L4[min(x4 + q + 1, W4 - 1)];
        const int off0 = ((x4 + q) << 2);   // left column for rm=0, j=0
        EMIT(A.x, A.y, A.z, A.w, 0)
        EMIT(A.y, A.z, A.w, Bv.x, 1)
        EMIT(A.z, A.w, Bv.x, Bv.y, 2)
        EMIT(A.w, Bv.x, Bv.y, Bv.z, 3)
        A = Bv;
    }
#undef EMIT
}

extern "C" void kernel_launch(void* const* d_in, const int* in_sizes, int n_in,
                              void* d_out, int out_size, void* d_ws, size_t ws_size,
                              hipStream_t stream) {
    const int*   img1  = (const int*)d_in[0];
    const int*   img2  = (const int*)d_in[1];
    const float* scale = (const float*)d_in[2];
    float*       out   = (float*)d_out;

    dim3 grid(HH, DD / DG, BB);  // 384 x 4 x 2 = 3072 blocks
    dim3 block(192);             // 3 waves per block, 32 stores per thread
    Hamming_34205119545967_kernel<<<grid, block, 0, stream>>>(img1, img2, scale, out);
}

// Round 5
// 301.649 us; speedup vs baseline: 1.0172x; 1.0172x over previous
//
#include <hip/hip_runtime.h>

// Problem constants (match reference)
constexpr int BB = 2;
constexpr int DD = 128;   // MAXDISP
constexpr int HH = 384;
constexpr int WW = 768;
constexpr int W4 = WW / 4;   // 192 int4/float4 per row
constexpr int DG = 32;       // disparities per block
constexpr int QG = DG / 4;   // int4-window steps per block (8)

typedef float __attribute__((ext_vector_type(4))) f32x4;

__global__ __launch_bounds__(192) void Hamming_34205119545967_kernel(
    const int* __restrict__ img1, const int* __restrict__ img2,
    const float* __restrict__ scale, float* __restrict__ out) {
    const int h  = blockIdx.x;   // 0..383
    const int dg = blockIdx.y;   // 0..3  (d group)
    const int b  = blockIdx.z;   // 0..1
    const int x4 = threadIdx.x;  // 0..191, one float4 column slice

    const int4* __restrict__ L4 =
        reinterpret_cast<const int4*>(img1 + ((size_t)b * HH + h) * WW);
    const int4* __restrict__ R4 =
        reinterpret_cast<const int4*>(img2 + ((size_t)b * HH + h) * WW);

    const int4  r = R4[x4];      // loop-invariant right word
    const float s = scale[0];

    int q = dg * QG;             // left-window word offset, d = 4q + rm
    int4 A = L4[min(x4 + q, W4 - 1)];

    const size_t drow = (size_t)HH * W4;  // f32x4 stride between d planes
    f32x4* __restrict__ obase = reinterpret_cast<f32x4*>(out) +
        (((size_t)b * DD + (dg * DG)) * HH + h) * W4 + x4;

#define EMIT(w0, w1, w2, w3, rm)                                       \
    {                                                                  \
        const int o_ = off0 + (rm);                                    \
        f32x4 o;                                                       \
        o.x = (o_ + 0 < WW) ? (float)__popc((w0) ^ r.x) * s : 0.0f;    \
        o.y = (o_ + 1 < WW) ? (float)__popc((w1) ^ r.y) * s : 0.0f;    \
        o.z = (o_ + 2 < WW) ? (float)__popc((w2) ^ r.z) * s : 0.0f;    \
        o.w = (o_ + 3 < WW) ? (float)__popc((w3) ^ r.w) * s : 0.0f;    \
        __builtin_nontemporal_store(o, obase + (size_t)(4 * qq + (rm)) * drow); \
    }

#pragma unroll
    for (int qq = 0; qq < QG; ++qq, ++q) {
        const int4 Bv = L4[min(x4 + q + 1, W4 - 1)];
        const int off0 = ((x4 + q) << 2);   // left column for rm=0, j=0
        EMIT(A.x, A.y, A.z, A.w, 0)
        EMIT(A.y, A.z, A.w, Bv.x, 1)
        EMIT(A.z, A.w, Bv.x, Bv.y, 2)
        EMIT(A.w, Bv.x, Bv.y, Bv.z, 3)
        A = Bv;
    }
#undef EMIT
}

extern "C" void kernel_launch(void* const* d_in, const int* in_sizes, int n_in,
                              void* d_out, int out_size, void* d_ws, size_t ws_size,
                              hipStream_t stream) {
    const int*   img1  = (const int*)d_in[0];
    const int*   img2  = (const int*)d_in[1];
    const float* scale = (const float*)d_in[2];
    float*       out   = (float*)d_out;

    dim3 grid(HH, DD / DG, BB);  // 384 x 4 x 2 = 3072 blocks
    dim3 block(192);             // 3 waves per block, 32 nt-stores per thread
    Hamming_34205119545967_kernel<<<grid, block, 0, stream>>>(img1, img2, scale, out);
}